// Round 9
// baseline (589.441 us; speedup 1.0000x reference)
//
#include <hip/hip_runtime.h>
#include <math.h>

// Problem shape (fixed by the reference setup_inputs):
#define B_DIM  8
#define T_DIM  256
#define U_DIM  100
#define U1_DIM 101
#define V_DIM  128

// Diagonal-major packed operand array (log2 domain, bf16):
//   cell (d,u) = uint32: low16 = bf16 blank-arrival bl(t-1,u),
//                        high16 = bf16 emit-arrival em(t,u-1),  t = d-u.
// Row = ROWU uints = 512 B (4 cache lines, aligned). Cells 0..103 used.
#define ROWU   128
#define DROWS  432
#define DEPTH  32          // asm-pinned register-pipeline depth (diagonals)
#define NEGF   (-8.0e29f)
#define FILLP  0xF122F122u // bf16(-1e30f) in both halves
#define LOG2E  1.4426950408889634f
#define LN2    0.69314718055994530942f

// MEASUREMENT ROUND: idempotent internal repeats to push lsm/dp above the
// harness's ~60us poison fills so rocprof top-5 shows their counters.
#define NREP_LSM 8
#define NREP_DP  16

typedef unsigned uv2 __attribute__((ext_vector_type(2)));

// log2-domain logaddexp; neg+abs fold into v_exp_f32 input modifiers.
__device__ __forceinline__ float logadd2(float a, float b) {
    float m = fmaxf(a, b);
    float e = exp2f(-fabsf(a - b));
    return m + log2f(1.0f + e);
}

// lane l <- lane l-1 (lane 0 gets 0), pure-VALU DPP wave_shr:1
__device__ __forceinline__ float lane_shr1(float x) {
    int r = __builtin_amdgcn_update_dpp(0, __builtin_bit_cast(int, x),
                                        0x138 /*wave_shr:1*/, 0xF, 0xF, true);
    return __builtin_bit_cast(float, r);
}

// fp32 -> bf16 (round-to-nearest-even)
__device__ __forceinline__ unsigned short f2bf(float f) {
    unsigned u = __builtin_bit_cast(unsigned, f);
    u += 0x7FFF + ((u >> 16) & 1);
    return (unsigned short)(u >> 16);
}

// Kernel 0: fill comb with NEGF pattern.
__global__ __launch_bounds__(256) void fill_kernel(uint4* __restrict__ p, int n4) {
    int i = blockIdx.x * 256 + threadIdx.x;
    if (i < n4) p[i] = make_uint4(FILLP, FILLP, FILLP, FILLP);
}

// Kernel 1: log-softmax over V=128 per (b,t,u) row, LOG2 domain, bf16 out.
// One 32-lane half-wave per row, float4 per lane. Rows that cannot influence
// alpha[tl,ul] are skipped. Body repeated NREP_LSM times (idempotent) for
// this round's measurement; memory clobber defeats cross-rep CSE.
__global__ __launch_bounds__(256) void lsm_kernel(
    const float* __restrict__ acts, const int* __restrict__ labels,
    const int* __restrict__ act_lens, const int* __restrict__ label_lens,
    unsigned short* __restrict__ comb, int nrows)
{
    int rid = blockIdx.x * 8 + (threadIdx.x >> 5);   // 8 rows per 256-thr block
    int hl = threadIdx.x & 31;                        // lane within 32-half

    #pragma unroll 1
    for (int rep = 0; rep < NREP_LSM; ++rep) {
        asm volatile("" ::: "memory");                // force real reloads per rep
        if (rid >= nrows) continue;

        int u  = rid % U1_DIM;
        int bt = rid / U1_DIM;          // b*T + t
        int b  = bt / T_DIM;
        int t  = bt - b * T_DIM;
        if (t >= act_lens[b] || u > label_lens[b]) continue;  // uniform per half-wave

        const float* row = acts + (size_t)rid * V_DIM;
        float4 x = *reinterpret_cast<const float4*>(row + 4 * hl);
        float4 y = make_float4(x.x * LOG2E, x.y * LOG2E, x.z * LOG2E, x.w * LOG2E);

        float s = exp2f(y.x) + exp2f(y.y) + exp2f(y.z) + exp2f(y.w);
        #pragma unroll
        for (int off = 16; off; off >>= 1) s += __shfl_xor(s, off);
        float lse2 = log2f(s);

        unsigned short* C = comb + (size_t)b * DROWS * (ROWU * 2);
        int d = t + u + 1;              // both outputs land on this diagonal row

        if (hl == 0)                    // bl(t,u) -> cell u low half
            C[(size_t)d * (ROWU * 2) + 2 * u] = f2bf(y.x - lse2);
        if (u < U_DIM) {
            int lab = labels[b * U_DIM + u];              // 0..127
            if (hl == (lab >> 2)) {
                int r = lab & 3;
                float v = (r == 0) ? y.x : (r == 1) ? y.y : (r == 2) ? y.z : y.w;
                // em(t,u) -> cell u+1 high half
                C[(size_t)d * (ROWU * 2) + 2 * u + 3] = f2bf(v - lse2);
            }
        }
    }
}

// Kernel 2: anti-diagonal DP, ONE wave per batch (structure identical to R8),
// repeated NREP_DP times (idempotent: pure function of comb -> loglike[b]).
__global__ __launch_bounds__(64, 1) void dp_kernel(
    const unsigned* __restrict__ comb,
    const int* __restrict__ act_lens, const int* __restrict__ label_lens,
    float* __restrict__ loglike)
{
    const int b = blockIdx.x;
    const int l = threadIdx.x;                  // 0..63

    #pragma unroll 1
    for (int rep = 0; rep < NREP_DP; ++rep) {
        asm volatile("" ::: "memory");
        const int tl   = act_lens[b] - 1;
        const int ul   = label_lens[b];
        const int dfin = tl + ul;               // in [177, 355]
        const unsigned* Cb = comb + (size_t)b * DROWS * ROWU + 2 * l;

        // final blank term bl(tl,ul): row dfin+1, cell ul, low half.
        unsigned fbu = comb[(size_t)b * DROWS * ROWU + (size_t)(dfin + 1) * ROWU + ul];
        float fin_bl = __builtin_bit_cast(float, fbu << 16);

        float v0 = (l == 0) ? 0.0f : NEGF;      // diagonal d=0: alpha[0,0]=0
        float v1 = NEGF;
        float rf0 = NEGF, rf1 = NEGF;

        asm volatile("s_waitcnt vmcnt(0)" ::: "memory");

        // Prime: operands for diagonals 1..32 (asm: cannot be sunk or elided).
        uv2 r[DEPTH];
        #pragma unroll
        for (int j = 0; j < DEPTH; ++j) {
            const unsigned* p = Cb + (size_t)(1 + j) * ROWU;
            asm volatile("global_load_dwordx2 %0, %1, off" : "=v"(r[j]) : "v"(p));
        }

        const int ngroups = (dfin + DEPTH - 1) / DEPTH;   // 6..12
        int d0 = 1;
        for (int g = 0; g < ngroups; ++g, d0 += DEPTH) {
            #pragma unroll
            for (int J = 0; J < DEPTH; ++J) {
                asm volatile("s_waitcnt vmcnt(31)");      // oldest load landed
                __builtin_amdgcn_sched_barrier(0);
                uv2 c = r[J];
                float bl0 = __builtin_bit_cast(float, c.x << 16);
                float em0 = __builtin_bit_cast(float, c.x & 0xFFFF0000u);
                float bl1 = __builtin_bit_cast(float, c.y << 16);
                float em1 = __builtin_bit_cast(float, c.y & 0xFFFF0000u);
                float left0 = lane_shr1(v1);    // prev diag u=2l-1 (lane0 dead)
                float a0 = v0 + bl0, p0 = left0 + em0;
                float a1 = v1 + bl1, p1 = v0 + em1;
                v0 = logadd2(a0, p0);
                v1 = logadd2(a1, p1);
                if (d0 + J == dfin) { rf0 = v0; rf1 = v1; }
                const unsigned* p = Cb + (size_t)(d0 + J + DEPTH) * ROWU; // <= 416 < DROWS
                asm volatile("global_load_dwordx2 %0, %1, off" : "=v"(r[J]) : "v"(p));
            }
        }

        float res = (ul & 1) ? rf1 : rf0;       // alpha[tl,ul] in lane ul>>1
        if (l == (ul >> 1)) {
            loglike[b] = LN2 * (res + fin_bl);
        }
    }
}

// Kernel 3: deterministic fixed-order reduction of the 8 per-batch loglikes.
__global__ void finalize_kernel(const float* __restrict__ loglike, float* __restrict__ out) {
    if (threadIdx.x == 0 && blockIdx.x == 0) {
        float s = 0.0f;
        #pragma unroll
        for (int i = 0; i < B_DIM; ++i) s += loglike[i];
        out[0] = -s / (float)B_DIM;
    }
}

extern "C" void kernel_launch(void* const* d_in, const int* in_sizes, int n_in,
                              void* d_out, int out_size, void* d_ws, size_t ws_size,
                              hipStream_t stream) {
    const float* acts       = (const float*)d_in[0];
    const int*   labels     = (const int*)d_in[1];
    const int*   act_lens   = (const int*)d_in[2];
    const int*   label_lens = (const int*)d_in[3];

    unsigned* comb    = (unsigned*)d_ws;                      // B*DROWS*ROWU uints (1.77 MB)
    float*    loglike = (float*)(comb + (size_t)B_DIM * DROWS * ROWU);

    int nrows   = B_DIM * T_DIM * U1_DIM;                     // 206,848
    int nblocks = (nrows + 7) / 8;                            // 8 rows per block

    int nfill4  = (B_DIM * DROWS * ROWU) / 4;                 // 110,592 uint4
    fill_kernel<<<(nfill4 + 255) / 256, 256, 0, stream>>>((uint4*)comb, nfill4);
    lsm_kernel<<<nblocks, 256, 0, stream>>>(acts, labels, act_lens, label_lens,
                                            (unsigned short*)comb, nrows);
    dp_kernel<<<B_DIM, 64, 0, stream>>>(comb, act_lens, label_lens, loglike);
    finalize_kernel<<<1, 64, 0, stream>>>(loglike, (float*)d_out);
}

// Round 10
// 58.506 us; speedup vs baseline: 10.0748x; 10.0748x over previous
//
#include <hip/hip_runtime.h>
#include <math.h>

// Problem shape (fixed by the reference setup_inputs):
#define B_DIM  8
#define T_DIM  256
#define U_DIM  100
#define U1_DIM 101
#define V_DIM  128

// comb: diagonal-major packed single-step operands (log2 domain, bf16):
//   cell (d,u) uint32: lo = bl(t-1,u), hi = em(t,u-1), t = d-u.
// Row = ROWU uints = 512 B. Cells 0..103 used, rest padding (FILLP).
#define ROWU   128
#define DROWS  432
// W: diagonal-major packed DOUBLE-step weights, row ri = dt-2 (dt = target diag):
//   cell u = 2 uints: {lo0=Wtop, hi0=Wmid, lo1=Wleft} bf16. Row = 128 cells = 1024 B.
#define WROWC  128
#define WROWS  428     // alloc per batch (incl. pipeline overrun pad); 355 written
#define NW_USED 355    // rows ri = 0..354  <=>  dt = 2..356
#define DEPTH  16      // dp asm-pinned pipeline depth (composed steps)
#define NEGF   (-8.0e29f)
#define FILLP  0xF122F122u // bf16(-1e30f) in both halves
#define LOG2E  1.4426950408889634f
#define LN2    0.69314718055994530942f

typedef unsigned uv2 __attribute__((ext_vector_type(2)));
typedef unsigned uv4 __attribute__((ext_vector_type(4)));

__device__ __forceinline__ float ubit(unsigned u) { return __builtin_bit_cast(float, u); }

// log2-domain logaddexp; neg+abs fold into v_exp_f32 input modifiers.
__device__ __forceinline__ float logadd2(float a, float b) {
    float m = fmaxf(a, b);
    float e = exp2f(-fabsf(a - b));
    return m + log2f(1.0f + e);
}

// log2-domain 3-way LSE; fmaxf pair fuses to v_max3_f32.
__device__ __forceinline__ float lse3(float a, float b, float c) {
    float m = fmaxf(fmaxf(a, b), c);
    float s = exp2f(a - m) + exp2f(b - m) + exp2f(c - m);
    return m + log2f(s);
}

// lane l <- lane l-1 (lane 0 gets 0), pure-VALU DPP wave_shr:1
__device__ __forceinline__ float lane_shr1(float x) {
    int r = __builtin_amdgcn_update_dpp(0, __builtin_bit_cast(int, x),
                                        0x138 /*wave_shr:1*/, 0xF, 0xF, true);
    return __builtin_bit_cast(float, r);
}

// fp32 -> bf16 (round-to-nearest-even)
__device__ __forceinline__ unsigned f2bf(float f) {
    unsigned u = __builtin_bit_cast(unsigned, f);
    u += 0x7FFF + ((u >> 16) & 1);
    return u >> 16;
}

// Kernel 0: fill comb with NEGF pattern; zero the completion counter.
__global__ __launch_bounds__(256) void fill_kernel(uint4* __restrict__ p, int n4,
                                                   int* __restrict__ counter) {
    int i = blockIdx.x * 256 + threadIdx.x;
    if (i < n4) p[i] = make_uint4(FILLP, FILLP, FILLP, FILLP);
    if (i == 0) *counter = 0;
}

// Kernel 1: log-softmax over V=128 per (b,t,u) row, LOG2 domain, bf16 out.
// One 32-lane half-wave per row, float4 per lane. Rows that cannot influence
// alpha[tl,ul] (t > tl or u > ul) are skipped (slots stay NEGF from fill).
__global__ __launch_bounds__(256) void lsm_kernel(
    const float* __restrict__ acts, const int* __restrict__ labels,
    const int* __restrict__ act_lens, const int* __restrict__ label_lens,
    unsigned short* __restrict__ comb, int nrows)
{
    int rid = blockIdx.x * 8 + (threadIdx.x >> 5);   // 8 rows per 256-thr block
    if (rid >= nrows) return;
    int hl = threadIdx.x & 31;                        // lane within 32-half

    int u  = rid % U1_DIM;
    int bt = rid / U1_DIM;          // b*T + t
    int b  = bt / T_DIM;
    int t  = bt - b * T_DIM;
    if (t >= act_lens[b] || u > label_lens[b]) return;   // uniform per half-wave

    const float* row = acts + (size_t)rid * V_DIM;
    float4 x = *reinterpret_cast<const float4*>(row + 4 * hl);
    float4 y = make_float4(x.x * LOG2E, x.y * LOG2E, x.z * LOG2E, x.w * LOG2E);

    float s = exp2f(y.x) + exp2f(y.y) + exp2f(y.z) + exp2f(y.w);
    #pragma unroll
    for (int off = 16; off; off >>= 1) s += __shfl_xor(s, off);
    float lse2 = log2f(s);

    unsigned short* C = comb + (size_t)b * DROWS * (ROWU * 2);
    int d = t + u + 1;              // both outputs land on this diagonal row

    if (hl == 0)                    // bl(t,u) -> cell u low half
        C[(size_t)d * (ROWU * 2) + 2 * u] = (unsigned short)f2bf(y.x - lse2);
    if (u < U_DIM) {
        int lab = labels[b * U_DIM + u];              // 0..127
        if (hl == (lab >> 2)) {
            int r = lab & 3;
            float v = (r == 0) ? y.x : (r == 1) ? y.y : (r == 2) ? y.z : y.w;
            // em(t,u) -> cell u+1 high half
            C[(size_t)d * (ROWU * 2) + 2 * u + 3] = (unsigned short)f2bf(v - lse2);
        }
    }
}

// Kernel 2: build DOUBLE-step weights from comb (all reads/writes coalesced,
// L2-resident; 2840 waves -> fully parallel). For target cell (dt, u):
//   alpha_dt[u] = LSE3(alpha_{dt-2}[u]   + Wtop[u],
//                      alpha_{dt-2}[u-1] + Wmid[u],
//                      alpha_{dt-2}[u-2] + Wleft[u])
//   Wtop  = BL_{dt-1}[u]   + BL_dt[u]
//   Wmid  = logadd2(EM_{dt-1}[u] + BL_dt[u], BL_{dt-1}[u-1] + EM_dt[u])
//   Wleft = EM_{dt-1}[u-1] + EM_dt[u]
// (algebra identical to the R6 kernel, which passed correctness checks)
__global__ __launch_bounds__(256) void w_kernel(
    const unsigned* __restrict__ comb, unsigned* __restrict__ W)
{
    int wid = blockIdx.x * 4 + (threadIdx.x >> 6);   // one wave per (b, row)
    int l   = threadIdx.x & 63;
    int b   = wid / NW_USED;
    int ri  = wid - b * NW_USED;                     // 0..354
    int dt  = ri + 2;                                // target diagonal

    const unsigned* C  = comb + ((size_t)b * DROWS + dt) * ROWU;
    const unsigned* Cm = C - ROWU;                   // row dt-1

    uv2 c0 = *(const uv2*)(C  + 2 * l);              // cells 2l, 2l+1 of row dt
    uv2 cm = *(const uv2*)(Cm + 2 * l);              // cells 2l, 2l+1 of row dt-1
    float BL0a = ubit(c0.x << 16), EM0a = ubit(c0.x & 0xFFFF0000u);
    float BL0b = ubit(c0.y << 16), EM0b = ubit(c0.y & 0xFFFF0000u);
    float BLma = ubit(cm.x << 16), EMma = ubit(cm.x & 0xFFFF0000u);
    float BLmb = ubit(cm.y << 16), EMmb = ubit(cm.y & 0xFFFF0000u);
    // cell 2l-1 of row dt-1 = lane (l-1)'s "b" values
    float BLmp = lane_shr1(BLmb);
    float EMmp = lane_shr1(EMmb);

    // cell A (u = 2l)
    float wtA = BLma + BL0a;
    float wmA = logadd2(EMma + BL0a, BLmp + EM0a);
    float wlA = EMmp + EM0a;
    // cell B (u = 2l+1)
    float wtB = BLmb + BL0b;
    float wmB = logadd2(EMmb + BL0b, BLma + EM0b);
    float wlB = EMma + EM0b;

    if (l == 0) { wmA = NEGF; wlA = NEGF; wlB = NEGF; }  // u=0 has no u-1/u-2; u=1 no u-2
    if (l >= 52) { wtA = wmA = wlA = wtB = wmB = wlB = NEGF; }  // u > 103: pad

    uv4 o;
    o.x = f2bf(wtA) | (f2bf(wmA) << 16);
    o.y = f2bf(wlA);
    o.z = f2bf(wtB) | (f2bf(wmB) << 16);
    o.w = f2bf(wlB);
    *(uv4*)(W + ((size_t)b * WROWS + ri) * (WROWC * 2) + 4 * l) = o;
}

// Kernel 3: DOUBLE-STEP anti-diagonal DP, ONE wave per batch, zero LDS ops.
// <=177 serial LSE3 steps (two diagonals each). Lane l owns u=2l (v0),
// 2l+1 (v1); neighbors via DPP. Operands: one asm-pinned dwordx4 per step,
// DEPTH=16 in flight, counted vmcnt(12) per 4-step sub-group.
// Final reduction fused via device-scope completion counter.
__global__ __launch_bounds__(64, 1) void dp_kernel(
    const unsigned* __restrict__ comb, const unsigned* __restrict__ W,
    const int* __restrict__ act_lens, const int* __restrict__ label_lens,
    float* __restrict__ loglike, int* __restrict__ counter,
    float* __restrict__ out)
{
    const int b = blockIdx.x;
    const int l = threadIdx.x;                  // 0..63
    const int tl    = act_lens[b] - 1;
    const int ul    = label_lens[b];
    const int dfin  = tl + ul;                  // in [177, 355]
    const int start = dfin & 1;                 // parity of the needed chain
    const int niter = dfin >> 1;                // composed steps to reach dfin

    const unsigned* combB = comb + (size_t)b * DROWS * ROWU;
    const char* Wbl = (const char*)(W + (size_t)b * WROWS * (WROWC * 2)) + 16 * l;

    // final blank term bl(tl,ul): comb row dfin+1, cell ul, low half
    unsigned fbu = combB[(size_t)(dfin + 1) * ROWU + ul];
    float fin_bl = ubit(fbu << 16);
    // odd-start init values: alpha[1,0]=bl(0,0), alpha[0,1]=em(0,0)
    unsigned i0 = combB[ROWU + 0];
    unsigned i1 = combB[ROWU + 1];

    float v0 = NEGF, v1 = NEGF;
    if (l == 0) {
        v0 = start ? ubit(i0 << 16) : 0.0f;
        v1 = start ? ubit(i1 & 0xFFFF0000u) : NEGF;
    }
    float rf0 = NEGF, rf1 = NEGF;

    asm volatile("s_waitcnt vmcnt(0)" ::: "memory");  // drain; vmcnt now exact

    // Prime: W rows for composed steps 0..15 (asm: cannot be sunk or elided).
    uv4 rW[DEPTH];
    #pragma unroll
    for (int j = 0; j < DEPTH; ++j) {
        const char* p = Wbl + (size_t)(start + 2 * j) * 1024;
        asm volatile("global_load_dwordx4 %0, %1, off" : "=v"(rW[j]) : "v"(p));
    }

    const int ngroups = (niter + DEPTH - 1) / DEPTH;  // <= 12
    for (int g = 0; g < ngroups; ++g) {
        const int it0 = g * DEPTH;
        // per-group reload base: W row (start + 2*it0 + 2*DEPTH)
        const char* gb = Wbl + (size_t)(start + 2 * it0 + 2 * DEPTH) * 1024;
        #pragma unroll
        for (int q = 0; q < 4; ++q) {
            asm volatile("s_waitcnt vmcnt(12)");      // oldest 4 loads landed
            __builtin_amdgcn_sched_barrier(0);
            #pragma unroll
            for (int j4 = 0; j4 < 4; ++j4) {
                const int J = q * 4 + j4;
                uv4 w = rW[J];
                float wtA = ubit(w.x << 16), wmA = ubit(w.x & 0xFFFF0000u);
                float wlA = ubit(w.y << 16);
                float wtB = ubit(w.z << 16), wmB = ubit(w.z & 0xFFFF0000u);
                float wlB = ubit(w.w << 16);
                float s1 = lane_shr1(v1);   // alpha[2l-1] (lane0: dead path)
                float s0 = lane_shr1(v0);   // alpha[2l-2]
                float nA = lse3(v0 + wtA, s1 + wmA, s0 + wlA);
                float nB = lse3(v1 + wtB, v0 + wmB, s1 + wlB);
                if (it0 + J == niter - 1) { rf0 = nA; rf1 = nB; }  // diag == dfin
                v0 = nA; v1 = nB;
                // reload slot J for composed step it+DEPTH
                const char* p = gb + (size_t)(2 * J) * 1024;
                asm volatile("global_load_dwordx4 %0, %1, off" : "=v"(rW[J]) : "v"(p));
            }
        }
    }

    float res = (ul & 1) ? rf1 : rf0;           // alpha[tl,ul] in lane ul>>1
    if (l == (ul >> 1)) {
        loglike[b] = LN2 * (res + fin_bl);
        __threadfence();                         // publish before signaling
        int old = atomicAdd(counter, 1);         // device-scope
        if (old == B_DIM - 1) {                  // last block finalizes
            __threadfence();
            float s = 0.0f;
            #pragma unroll
            for (int i = 0; i < B_DIM; ++i)
                s += __hip_atomic_load(&loglike[i], __ATOMIC_RELAXED,
                                       __HIP_MEMORY_SCOPE_AGENT);
            out[0] = -s / (float)B_DIM;
        }
    }
}

extern "C" void kernel_launch(void* const* d_in, const int* in_sizes, int n_in,
                              void* d_out, int out_size, void* d_ws, size_t ws_size,
                              hipStream_t stream) {
    const float* acts       = (const float*)d_in[0];
    const int*   labels     = (const int*)d_in[1];
    const int*   act_lens   = (const int*)d_in[2];
    const int*   label_lens = (const int*)d_in[3];

    unsigned* comb    = (unsigned*)d_ws;                          // 1.77 MB
    unsigned* W       = comb + (size_t)B_DIM * DROWS * ROWU;      // 3.5 MB
    float*    loglike = (float*)(W + (size_t)B_DIM * WROWS * (WROWC * 2));
    int*      counter = (int*)(loglike + B_DIM);

    int nrows   = B_DIM * T_DIM * U1_DIM;                     // 206,848
    int nblocks = (nrows + 7) / 8;                            // 8 rows per block

    int nfill4  = (B_DIM * DROWS * ROWU) / 4;                 // comb only
    fill_kernel<<<(nfill4 + 255) / 256, 256, 0, stream>>>((uint4*)comb, nfill4, counter);
    lsm_kernel<<<nblocks, 256, 0, stream>>>(acts, labels, act_lens, label_lens,
                                            (unsigned short*)comb, nrows);
    int wwaves  = B_DIM * NW_USED;                            // 2840 waves
    w_kernel<<<(wwaves + 3) / 4, 256, 0, stream>>>(comb, W);
    dp_kernel<<<B_DIM, 64, 0, stream>>>(comb, W, act_lens, label_lens,
                                        loglike, counter, (float*)d_out);
}

// Round 11
// 56.912 us; speedup vs baseline: 10.3571x; 1.0280x over previous
//
#include <hip/hip_runtime.h>
#include <math.h>

// Problem shape (fixed by the reference setup_inputs):
#define B_DIM  8
#define T_DIM  256
#define U_DIM  100
#define U1_DIM 101
#define V_DIM  128

// comb: diagonal-major packed single-step operands (log2 domain, bf16):
//   cell (d,u) uint32: lo = bl(t-1,u) [BL_d[u]], hi = em(t,u-1) [EM_d[u]], t=d-u.
// Row = ROWU uints = 512 B. Rows 0..356 used.
#define ROWU   128
#define DROWS  360
// V: 4-step banded weights. Row ri = dt-4 (dt = target diag, 4..355).
//   3 planes of 104 uints per row: plane0 = V0|V1, plane1 = V2|V3, plane2 = V4.
//   alpha_dt[u] = LSE5_k( alpha_{dt-4}[u-k] + Vk[dt,u] ), k = 0..4.
#define NV     352         // rows written (ri = 0..351)
#define VROWS  418         // rows allocated (clamped reads + lane-bleed pad)
#define VROWB  1280        // bytes/row (3*416 = 1248, padded)
#define PL     416         // plane stride in bytes
#define DEPTH  16          // dp pipeline depth (composed steps in flight)
#define NEGF   (-8.0e29f)
#define FILLP  0xF122F122u // bf16(-1e30f) in both halves
#define LOG2E  1.4426950408889634f
#define LN2    0.69314718055994530942f

typedef unsigned uv2 __attribute__((ext_vector_type(2)));

__device__ __forceinline__ float ubit(unsigned u) { return __builtin_bit_cast(float, u); }

// log2-domain logaddexp (finite operands only)
__device__ __forceinline__ float logadd2(float a, float b) {
    float m = fmaxf(a, b);
    float e = exp2f(-fabsf(a - b));
    return m + log2f(1.0f + e);
}
__device__ __forceinline__ float lse3(float a, float b, float c) {
    float m = fmaxf(fmaxf(a, b), c);
    float s = exp2f(a - m) + exp2f(b - m) + exp2f(c - m);
    return m + log2f(s);
}
__device__ __forceinline__ float lse5(float a, float b, float c, float d, float e) {
    float m = fmaxf(fmaxf(fmaxf(a, b), c), fmaxf(d, e));
    float s = exp2f(a - m) + exp2f(b - m) + exp2f(c - m) + exp2f(d - m) + exp2f(e - m);
    return m + log2f(s);
}

// lane l <- lane l-1 (lane 0 gets 0), pure-VALU DPP wave_shr:1
__device__ __forceinline__ float lane_shr1(float x) {
    int r = __builtin_amdgcn_update_dpp(0, __builtin_bit_cast(int, x),
                                        0x138 /*wave_shr:1*/, 0xF, 0xF, true);
    return __builtin_bit_cast(float, r);
}

// fp32 -> bf16 (round-to-nearest-even)
__device__ __forceinline__ unsigned f2bf(float f) {
    unsigned u = __builtin_bit_cast(unsigned, f);
    u += 0x7FFF + ((u >> 16) & 1);
    return u >> 16;
}

// 2-step weights for one diagonal row pair (verified algebra from R10 w_kernel):
// maps alpha_{d-2} -> alpha_d:  tA/mA/lA for u=2l, tB/mB/lB for u=2l+1.
struct W2 { float tA, mA, lA, tB, mB, lB; };
__device__ __forceinline__ W2 buildW2(uv2 c0 /*row d*/, uv2 cm /*row d-1*/, int l) {
    float BL0a = ubit(c0.x << 16), EM0a = ubit(c0.x & 0xFFFF0000u);
    float BL0b = ubit(c0.y << 16), EM0b = ubit(c0.y & 0xFFFF0000u);
    float BLma = ubit(cm.x << 16), EMma = ubit(cm.x & 0xFFFF0000u);
    float BLmb = ubit(cm.y << 16), EMmb = ubit(cm.y & 0xFFFF0000u);
    float BLmp = lane_shr1(BLmb), EMmp = lane_shr1(EMmb);   // cell 2l-1 of row d-1
    W2 w;
    w.tA = BLma + BL0a;
    w.mA = logadd2(EMma + BL0a, BLmp + EM0a);
    w.lA = EMmp + EM0a;
    w.tB = BLmb + BL0b;
    w.mB = logadd2(EMmb + BL0b, BLma + EM0b);
    w.lB = EMma + EM0b;
    if (l == 0) { w.mA = NEGF; w.lA = NEGF; w.lB = NEGF; }  // u=0/1 boundaries
    return w;
}

// Kernel 0: fill comb with NEGF pattern; zero the completion counter.
__global__ __launch_bounds__(256) void fill_kernel(uint4* __restrict__ p, int n4,
                                                   int* __restrict__ counter) {
    int i = blockIdx.x * 256 + threadIdx.x;
    if (i < n4) p[i] = make_uint4(FILLP, FILLP, FILLP, FILLP);
    if (i == 0) *counter = 0;
}

// Kernel 1: log-softmax over V=128 per (b,t,u) row, LOG2 domain, bf16 out.
// One 32-lane half-wave per row, float4 per lane. Rows with t>tl or u>ul are
// skipped entirely (slots stay NEGF from fill) -> ~40% less read traffic.
__global__ __launch_bounds__(256) void lsm_kernel(
    const float* __restrict__ acts, const int* __restrict__ labels,
    const int* __restrict__ act_lens, const int* __restrict__ label_lens,
    unsigned short* __restrict__ comb, int nrows)
{
    int rid = blockIdx.x * 8 + (threadIdx.x >> 5);   // 8 rows per 256-thr block
    if (rid >= nrows) return;
    int hl = threadIdx.x & 31;                        // lane within 32-half

    int u  = rid % U1_DIM;
    int bt = rid / U1_DIM;          // b*T + t
    int b  = bt / T_DIM;
    int t  = bt - b * T_DIM;
    if (t >= act_lens[b] || u > label_lens[b]) return;   // uniform per half-wave

    const float* row = acts + (size_t)rid * V_DIM;
    float4 x = *reinterpret_cast<const float4*>(row + 4 * hl);
    float4 y = make_float4(x.x * LOG2E, x.y * LOG2E, x.z * LOG2E, x.w * LOG2E);

    float s = exp2f(y.x) + exp2f(y.y) + exp2f(y.z) + exp2f(y.w);
    #pragma unroll
    for (int off = 16; off; off >>= 1) s += __shfl_xor(s, off);
    float lse2 = log2f(s);

    unsigned short* C = comb + (size_t)b * DROWS * (ROWU * 2);
    int d = t + u + 1;              // both outputs land on this diagonal row

    if (hl == 0)                    // bl(t,u) -> cell u low half
        C[(size_t)d * (ROWU * 2) + 2 * u] = (unsigned short)f2bf(y.x - lse2);
    if (u < U_DIM) {
        int lab = labels[b * U_DIM + u];              // 0..127
        if (hl == (lab >> 2)) {
            int r = lab & 3;
            float v = (r == 0) ? y.x : (r == 1) ? y.y : (r == 2) ? y.z : y.w;
            // em(t,u) -> cell u+1 high half
            C[(size_t)d * (ROWU * 2) + 2 * u + 3] = (unsigned short)f2bf(v - lse2);
        }
    }
}

// Kernel 2: build 4-step weights V[dt] = W2[dt] o W2[dt-2], both W2s computed
// inline from comb (coalesced, L2-resident; one wave per (b,dt); fully parallel).
// NEGF propagation kills all out-of-band paths (traced for u=0..3); only lane0
// cell-a needs explicit override.
__global__ __launch_bounds__(256) void v_kernel(
    const unsigned* __restrict__ comb, unsigned* __restrict__ V)
{
    int wid = blockIdx.x * 4 + (threadIdx.x >> 6);
    if (wid >= B_DIM * NV) return;
    int l  = threadIdx.x & 63;
    int b  = wid / NV;
    int ri = wid - b * NV;                  // 0..351
    int dt = ri + 4;                        // target diagonal (4..355)

    const unsigned* C = comb + ((size_t)b * DROWS + dt) * ROWU + 2 * l;
    uv2 c0 = *(const uv2*)(C);              // row dt
    uv2 c1 = *(const uv2*)(C - ROWU);       // row dt-1
    uv2 c2 = *(const uv2*)(C - 2 * ROWU);   // row dt-2
    uv2 c3 = *(const uv2*)(C - 3 * ROWU);   // row dt-3

    W2 P = buildW2(c0, c1, l);              // alpha_{dt-2} -> alpha_dt
    W2 Q = buildW2(c2, c3, l);              // alpha_{dt-4} -> alpha_{dt-2}

    float Qt_b1 = lane_shr1(Q.tB), Qm_b1 = lane_shr1(Q.mB), Ql_b1 = lane_shr1(Q.lB); // Q[2l-1]
    float Qt_a1 = lane_shr1(Q.tA), Qm_a1 = lane_shr1(Q.mA), Ql_a1 = lane_shr1(Q.lA); // Q[2l-2]

    // cell a (u = 2l)
    float V0a = P.tA + Q.tA;
    float V1a = logadd2(P.tA + Q.mA, P.mA + Qt_b1);
    float V2a = lse3(P.tA + Q.lA, P.mA + Qm_b1, P.lA + Qt_a1);
    float V3a = logadd2(P.mA + Ql_b1, P.lA + Qm_a1);
    float V4a = P.lA + Ql_a1;
    // cell b (u = 2l+1)
    float V0b = P.tB + Q.tB;
    float V1b = logadd2(P.tB + Q.mB, P.mB + Q.tA);
    float V2b = lse3(P.tB + Q.lB, P.mB + Q.mA, P.lB + Qt_b1);
    float V3b = logadd2(P.mB + Q.lA, P.lB + Qm_b1);
    float V4b = P.lB + Ql_b1;

    if (l == 0) { V1a = NEGF; V2a = NEGF; V3a = NEGF; V4a = NEGF; }  // u=0: no u-k

    if (l < 52) {                            // cells 0..103 only; don't clobber planes
        char* row = (char*)V + ((size_t)b * VROWS + ri) * VROWB + 8 * l;
        uv2 p0, p1, p2;
        p0.x = f2bf(V0a) | (f2bf(V1a) << 16);  p0.y = f2bf(V0b) | (f2bf(V1b) << 16);
        p1.x = f2bf(V2a) | (f2bf(V3a) << 16);  p1.y = f2bf(V2b) | (f2bf(V3b) << 16);
        p2.x = f2bf(V4a);                      p2.y = f2bf(V4b);
        *(uv2*)(row)          = p0;
        *(uv2*)(row + PL)     = p1;
        *(uv2*)(row + 2 * PL) = p2;
    }
}

// Kernel 3: QUAD-STEP anti-diagonal DP, ONE wave per batch, zero LDS ops.
// <=88 serial LSE5 steps (four diagonals each). Lane l owns u=2l (v0),
// 2l+1 (v1); neighbors u-1..u-4 via 4 chained DPP shifts. Operands: 3
// asm-pinned dwordx2 per step, DEPTH=16 (48 loads in flight), counted
// vmcnt(36) per 4-step sub-group. Final reduction fused via counter.
__global__ __launch_bounds__(64, 1) void dp_kernel(
    const unsigned* __restrict__ comb, const unsigned* __restrict__ V,
    const int* __restrict__ act_lens, const int* __restrict__ label_lens,
    float* __restrict__ loglike, int* __restrict__ counter,
    float* __restrict__ out)
{
    const int b = blockIdx.x;
    const int l = threadIdx.x;                  // 0..63
    const int tl    = act_lens[b] - 1;
    const int ul    = label_lens[b];
    const int dfin  = tl + ul;                  // in [177, 355]
    const int start = dfin & 3;                 // parity class (0..3)
    const int niter = dfin >> 2;                // composed steps (43..88)

    const unsigned* combB = comb + (size_t)b * DROWS * ROWU;
    const char* Vb = (const char*)V + (size_t)b * VROWS * VROWB + 8 * l;

    // final blank term bl(tl,ul): comb row dfin+1 (<360), cell ul, low half
    unsigned fbu = combB[(size_t)(dfin + 1) * ROWU + ul];
    float fin_bl = ubit(fbu << 16);

    // state at diag 0, then <=3 manual single steps to reach diag `start`
    float v0 = (l == 0) ? 0.0f : NEGF;
    float v1 = NEGF;
    for (int d = 1; d <= start; ++d) {
        uv2 c = *(const uv2*)(combB + (size_t)d * ROWU + 2 * l);
        float bl0 = ubit(c.x << 16), em0 = ubit(c.x & 0xFFFF0000u);
        float bl1 = ubit(c.y << 16), em1 = ubit(c.y & 0xFFFF0000u);
        float left0 = lane_shr1(v1);
        float a0 = v0 + bl0, p0 = left0 + em0;
        float a1 = v1 + bl1, p1 = v0 + em1;
        v0 = logadd2(a0, p0);
        v1 = logadd2(a1, p1);
    }
    float rf0 = NEGF, rf1 = NEGF;

    asm volatile("s_waitcnt vmcnt(0)" ::: "memory");  // drain; vmcnt now exact

    // Prime: V rows for composed steps 0..15 (asm: cannot be sunk or elided).
    uv2 r0[DEPTH], r1[DEPTH], r2[DEPTH];
    #pragma unroll
    for (int j = 0; j < DEPTH; ++j) {
        int rr = start + 4 * j; rr = rr < VROWS - 2 ? rr : VROWS - 3;   // uniform clamp
        const char* p = Vb + (size_t)rr * VROWB;
        asm volatile("global_load_dwordx2 %0, %1, off" : "=v"(r0[j]) : "v"(p));
        asm volatile("global_load_dwordx2 %0, %1, off" : "=v"(r1[j]) : "v"(p + PL));
        asm volatile("global_load_dwordx2 %0, %1, off" : "=v"(r2[j]) : "v"(p + 2 * PL));
    }

    const int ngroups = (niter + DEPTH - 1) / DEPTH;  // <= 6
    for (int g = 0; g < ngroups; ++g) {
        const int it0 = g * DEPTH;
        #pragma unroll
        for (int q = 0; q < 4; ++q) {
            asm volatile("s_waitcnt vmcnt(36)");      // oldest 4 slots (12 loads) landed
            __builtin_amdgcn_sched_barrier(0);
            #pragma unroll
            for (int j4 = 0; j4 < 4; ++j4) {
                const int J = q * 4 + j4;
                const int it = it0 + J;
                uv2 a0 = r0[J], a1 = r1[J], a2 = r2[J];
                float V0a = ubit(a0.x << 16), V1a = ubit(a0.x & 0xFFFF0000u);
                float V0b = ubit(a0.y << 16), V1b = ubit(a0.y & 0xFFFF0000u);
                float V2a = ubit(a1.x << 16), V3a = ubit(a1.x & 0xFFFF0000u);
                float V2b = ubit(a1.y << 16), V3b = ubit(a1.y & 0xFFFF0000u);
                float V4a = ubit(a2.x << 16), V4b = ubit(a2.y << 16);
                float s1 = lane_shr1(v1);   // alpha[2l-1]
                float s0 = lane_shr1(v0);   // alpha[2l-2]
                float s3 = lane_shr1(s1);   // alpha[2l-3]
                float s2 = lane_shr1(s0);   // alpha[2l-4]
                float nA = lse5(v0 + V0a, s1 + V1a, s0 + V2a, s3 + V3a, s2 + V4a);
                float nB = lse5(v1 + V0b, v0 + V1b, s1 + V2b, s0 + V3b, s3 + V4b);
                if (it == niter - 1) { rf0 = nA; rf1 = nB; }   // diag == dfin
                v0 = nA; v1 = nB;
                int rr = start + 4 * (it + DEPTH); rr = rr < VROWS - 2 ? rr : VROWS - 3;
                const char* p = Vb + (size_t)rr * VROWB;
                asm volatile("global_load_dwordx2 %0, %1, off" : "=v"(r0[J]) : "v"(p));
                asm volatile("global_load_dwordx2 %0, %1, off" : "=v"(r1[J]) : "v"(p + PL));
                asm volatile("global_load_dwordx2 %0, %1, off" : "=v"(r2[J]) : "v"(p + 2 * PL));
            }
        }
    }

    float res = (ul & 1) ? rf1 : rf0;           // alpha[tl,ul] in lane ul>>1
    if (l == (ul >> 1)) {
        loglike[b] = LN2 * (res + fin_bl);
        __threadfence();                         // publish before signaling
        int old = atomicAdd(counter, 1);         // device-scope
        if (old == B_DIM - 1) {                  // last block finalizes
            __threadfence();
            float s = 0.0f;
            #pragma unroll
            for (int i = 0; i < B_DIM; ++i)
                s += __hip_atomic_load(&loglike[i], __ATOMIC_RELAXED,
                                       __HIP_MEMORY_SCOPE_AGENT);
            out[0] = -s / (float)B_DIM;
        }
    }
}

extern "C" void kernel_launch(void* const* d_in, const int* in_sizes, int n_in,
                              void* d_out, int out_size, void* d_ws, size_t ws_size,
                              hipStream_t stream) {
    const float* acts       = (const float*)d_in[0];
    const int*   labels     = (const int*)d_in[1];
    const int*   act_lens   = (const int*)d_in[2];
    const int*   label_lens = (const int*)d_in[3];

    unsigned* comb    = (unsigned*)d_ws;                          // 1.47 MB
    unsigned* V       = comb + (size_t)B_DIM * DROWS * ROWU;      // 4.28 MB
    float*    loglike = (float*)((char*)V + (size_t)B_DIM * VROWS * VROWB);
    int*      counter = (int*)(loglike + B_DIM);

    int nrows   = B_DIM * T_DIM * U1_DIM;                     // 206,848
    int nblocks = (nrows + 7) / 8;                            // 8 rows per block

    int nfill4  = (B_DIM * DROWS * ROWU) / 4;                 // 92,160 uint4
    fill_kernel<<<(nfill4 + 255) / 256, 256, 0, stream>>>((uint4*)comb, nfill4, counter);
    lsm_kernel<<<nblocks, 256, 0, stream>>>(acts, labels, act_lens, label_lens,
                                            (unsigned short*)comb, nrows);
    int vwaves = B_DIM * NV;                                  // 2816 waves
    v_kernel<<<(vwaves + 3) / 4, 256, 0, stream>>>(comb, V);
    dp_kernel<<<B_DIM, 64, 0, stream>>>(comb, V, act_lens, label_lens,
                                        loglike, counter, (float*)d_out);
}